// Round 1
// 427.594 us; speedup vs baseline: 1.0662x; 1.0662x over previous
//
#include <hip/hip_runtime.h>
#include <math.h>

#define NNODES 50000
#define NPAD 50176         // padded rows for unguarded global_load_lds staging
#define FIN 512
#define HID 64
#define HEADS 4
#define HD (HEADS * HID)   // 256
#define NCLS 40
#define NCLSP 64           // padded to 4x16 MFMA n-tiles; pow2 for 8-lane-per-edge agg2
#define NEG_SLOPE 0.2f
#define SBLK 256
#define NSCAN ((NNODES + SBLK - 1) / SBLK)   // 196

typedef __attribute__((ext_vector_type(8))) short short8;
typedef __attribute__((ext_vector_type(4))) float f32x4;

static __device__ inline unsigned short f2bf(float f) {
    unsigned int u = __builtin_bit_cast(unsigned int, f);
    unsigned int r = (u + 0x7FFFu + ((u >> 16) & 1u)) >> 16;
    return (unsigned short)r;
}
static __device__ inline float bf2f(unsigned short b) {
    return __builtin_bit_cast(float, (unsigned int)b << 16);
}
static __device__ inline void gload_lds16(const unsigned short* g, unsigned short* l) {
    __builtin_amdgcn_global_load_lds(
        (const __attribute__((address_space(1))) unsigned int*)g,
        (__attribute__((address_space(3))) unsigned int*)l, 16, 0, 0);
}

// ---------------- x cast: x[50000,512] fp32 -> xb[50176,512] bf16 (pad=0) ----
__global__ __launch_bounds__(256) void xcast_kernel(const float* __restrict__ x,
                                                    unsigned short* __restrict__ xb) {
    const size_t idx = ((size_t)blockIdx.x * 256 + threadIdx.x) * 8;
    if (idx < (size_t)NNODES * FIN) {
        const float4 v0 = *(const float4*)&x[idx];
        const float4 v1 = *(const float4*)&x[idx + 4];
        ushort4 p0, p1;
        p0.x = f2bf(v0.x); p0.y = f2bf(v0.y); p0.z = f2bf(v0.z); p0.w = f2bf(v0.w);
        p1.x = f2bf(v1.x); p1.y = f2bf(v1.y); p1.z = f2bf(v1.z); p1.w = f2bf(v1.w);
        *(ushort4*)&xb[idx] = p0;
        *(ushort4*)&xb[idx + 4] = p1;
    } else {
        const ushort4 z = {0, 0, 0, 0};
        *(ushort4*)&xb[idx] = z;
        *(ushort4*)&xb[idx + 4] = z;
    }
}

// ---------------- W1 cast+transpose: W1[512,256] fp32 -> W1t[256,512] bf16 ---
__global__ __launch_bounds__(256) void w1t_kernel(const float* __restrict__ W1,
                                                  unsigned short* __restrict__ W1t) {
    const int idx = blockIdx.x * 256 + threadIdx.x;
    const int k = idx >> 8;          // 0..511
    const int n = idx & 255;         // 0..255
    W1t[n * FIN + k] = f2bf(W1[idx]);
}

// ---------------- W2 cast+transpose: W2[256,40] fp32 -> W2t[64][256] bf16 ----
// rows 40..63 are zero -> gemm2 writes exact zeros into h2 pad columns
__global__ __launch_bounds__(256) void w2t_kernel(const float* __restrict__ W2,
                                                  unsigned short* __restrict__ W2t) {
    const int idx = blockIdx.x * 256 + threadIdx.x;  // 64 blocks
    const int n = idx >> 8;          // 0..63
    const int k = idx & 255;         // 0..255
    W2t[n * HD + k] = (n < NCLS) ? f2bf(W2[k * NCLS + n]) : (unsigned short)0;
}

// ---------------- GEMM1 v2: BM=64, BN=256 (full-width rows) + fused al1 ------
// xb read exactly once (no y-split); W1t (256KB) is L2-resident. Wave w's
// 64-col slice == head w, so per-head score dots complete within-wave.
#define BM 64
#define BN 256
#define BK 32

__global__ __launch_bounds__(256) void gemm1_kernel(const unsigned short* __restrict__ xb,
                                                    const unsigned short* __restrict__ W1t,
                                                    const float* __restrict__ a_src,
                                                    const float* __restrict__ a_dst,
                                                    unsigned short* __restrict__ h1,
                                                    float* __restrict__ al_s,
                                                    float* __restrict__ al_d) {
    __shared__ unsigned short As[BM * BK];  // 4 KB  [m][k] (DMA layout)
    __shared__ unsigned short Bs[BN * BK];  // 16 KB [n][k]
    const int tid = threadIdx.x;
    const int wave = tid >> 6;
    const int lane = tid & 63;
    const int quad = lane >> 4;
    const int col = lane & 15;
    const int m0 = blockIdx.x * BM;
    // staging: wave-uniform LDS base + lane*16B; lane covers 4-lanes-per-row
    const int srow = lane >> 2;          // 0..15 within a 16-row group
    const int skk = (lane & 3) * 8;      // 8-elem (16B) k-chunk

    f32x4 acc[4][4] = {};

    for (int k0 = 0; k0 < FIN; k0 += BK) {
        // A: 64 rows x 32k = 4KB = 256 lanes x 16B (one DMA per thread)
        {
            const int r = wave * 16 + srow;
            gload_lds16(&xb[(size_t)(m0 + r) * FIN + k0 + skk], &As[r * BK + skk]);
        }
        // B: 256 rows x 32k = 16KB (four DMAs per thread)
        #pragma unroll
        for (int c = 0; c < 4; ++c) {
            const int r = c * 64 + wave * 16 + srow;
            gload_lds16(&W1t[(size_t)r * FIN + k0 + skk], &Bs[r * BK + skk]);
        }
        __syncthreads();

        short8 af[4], bf[4];
        #pragma unroll
        for (int i = 0; i < 4; ++i)
            af[i] = *(const short8*)&As[(i * 16 + col) * BK + quad * 8];
        #pragma unroll
        for (int j = 0; j < 4; ++j)
            bf[j] = *(const short8*)&Bs[(wave * 64 + j * 16 + col) * BK + quad * 8];
        #pragma unroll
        for (int i = 0; i < 4; ++i)
            #pragma unroll
            for (int j = 0; j < 4; ++j)
                acc[i][j] = __builtin_amdgcn_mfma_f32_16x16x32_bf16(af[i], bf[j], acc[i][j], 0, 0, 0);
        __syncthreads();
    }

    // epilogue: D row = quad*4 + reg (within i*16 tile), col c = wave*64+j*16+col
    // h1 write + fused per-head attention score dots (head == wave)
    float asv[4], adv[4];
    #pragma unroll
    for (int j = 0; j < 4; ++j) {
        asv[j] = a_src[wave * 64 + j * 16 + col];
        adv[j] = a_dst[wave * 64 + j * 16 + col];
    }
    #pragma unroll
    for (int i = 0; i < 4; ++i) {
        #pragma unroll
        for (int reg = 0; reg < 4; ++reg) {
            const int row = i * 16 + quad * 4 + reg;
            const int gm = m0 + row;
            float ds = 0.f, dd = 0.f;
            #pragma unroll
            for (int j = 0; j < 4; ++j) {
                const float v = acc[i][j][reg];
                ds = fmaf(v, asv[j], ds);
                dd = fmaf(v, adv[j], dd);
                if (gm < NNODES) {
                    const int gc = wave * 64 + j * 16 + col;
                    h1[(size_t)gm * HD + gc] = f2bf(v);
                }
            }
            // reduce over the 16 col-lanes (same quad group)
            #pragma unroll
            for (int off = 1; off < 16; off <<= 1) {
                ds += __shfl_xor(ds, off);
                dd += __shfl_xor(dd, off);
            }
            if (col == 0 && gm < NNODES) {
                al_s[gm * HEADS + wave] = ds;
                al_d[gm * HEADS + wave] = dd;
            }
        }
    }
}

// ---------------- CSR build --------------------------------------------------
__global__ void deg_kernel(const int* __restrict__ ei, int E, int* __restrict__ deg) {
    const int e = blockIdx.x * 256 + threadIdx.x;
    if (e < E) atomicAdd(&deg[ei[E + e]], 1);
}

// hierarchical exclusive scan over deg[50000]
__global__ __launch_bounds__(SBLK) void scan1_kernel(const int* __restrict__ deg,
                                                     int* __restrict__ psum,
                                                     int* __restrict__ bsum) {
    __shared__ int ws[4];
    const int t = threadIdx.x;
    const int idx = blockIdx.x * SBLK + t;
    const int lane = t & 63;
    const int w = t >> 6;
    int sv = (idx < NNODES) ? deg[idx] : 0;
    #pragma unroll
    for (int off = 1; off < 64; off <<= 1) {
        const int n = __shfl_up(sv, off);
        if (lane >= off) sv += n;
    }
    if (lane == 63) ws[w] = sv;
    __syncthreads();
    int add = 0;
    for (int i = 0; i < w; ++i) add += ws[i];
    sv += add;
    if (idx < NNODES) psum[idx] = sv;
    if (t == SBLK - 1) bsum[blockIdx.x] = sv;
}

__global__ __launch_bounds__(SBLK) void scan2_kernel(int* __restrict__ bsum,
                                                     int* __restrict__ offsets) {
    __shared__ int ws[4];
    const int t = threadIdx.x;
    const int lane = t & 63;
    const int w = t >> 6;
    int sv = (t < NSCAN) ? bsum[t] : 0;
    #pragma unroll
    for (int off = 1; off < 64; off <<= 1) {
        const int n = __shfl_up(sv, off);
        if (lane >= off) sv += n;
    }
    if (lane == 63) ws[w] = sv;
    __syncthreads();
    int add = 0;
    for (int i = 0; i < w; ++i) add += ws[i];
    sv += add;
    if (t < NSCAN) bsum[t] = sv;
    if (t == SBLK - 1) offsets[NNODES] = sv;
}

__global__ __launch_bounds__(SBLK) void scan3_kernel(const int* __restrict__ deg,
                                                     const int* __restrict__ psum,
                                                     const int* __restrict__ bsum,
                                                     int* __restrict__ offsets) {
    const int b = blockIdx.x;
    const int idx = b * SBLK + threadIdx.x;
    if (idx < NNODES) {
        const int boff = (b > 0) ? bsum[b - 1] : 0;
        offsets[idx] = psum[idx] - deg[idx] + boff;
    }
}

__global__ void scatter_kernel(const int* __restrict__ ei, int E,
                               const int* __restrict__ offsets,
                               int* __restrict__ cursor,
                               int* __restrict__ csr_src) {
    const int e = blockIdx.x * 256 + threadIdx.x;
    if (e < E) {
        const int dst = ei[E + e];
        const int src = ei[e];
        const int pos = offsets[dst] + atomicAdd(&cursor[dst], 1);
        csr_src[pos] = src;
    }
}

// ---------------- layer-1 aggregation: quarter-wave-per-edge, 4 streams ------
// 16 lanes x 32B (16 bf16 feats) cover the full 256-feat row; 4 edges in
// flight per wave doubles outstanding gathers vs the old half-wave scheme.
__global__ __launch_bounds__(256) void agg1_kernel(const unsigned short* __restrict__ h1,
                                                   const float* __restrict__ al_s,
                                                   const float* __restrict__ al_d,
                                                   const int* __restrict__ offsets,
                                                   const int* __restrict__ csr_src,
                                                   const float* __restrict__ b1,
                                                   unsigned short* __restrict__ h_act) {
    const int node = (blockIdx.x * 256 + threadIdx.x) >> 6;
    const int lane = threadIdx.x & 63;
    const int q = lane >> 4;         // edge stream 0..3
    const int fl = lane & 15;        // feature group: feats fl*16 .. fl*16+15
    const int h = fl >> 2;           // head for this feature group
    const float ad = al_d[node * HEADS + h];
    const int start = offsets[node];
    const int end = offsets[node + 1];
    const int last = end - 1;

    float s = 0.f;
    float acc[16] = {};

    {
        const int idx = start + q;
        const int src0 = csr_src[min(idx, last)];
        float sc = (idx < end) ? al_s[src0 * HEADS + h] : -__builtin_inff();
        short8 v0 = *(const short8*)&h1[(size_t)src0 * HD + fl * 16];
        short8 v1 = *(const short8*)&h1[(size_t)src0 * HD + fl * 16 + 8];

        for (int i = start; i < end; i += 4) {
            const int j = i + 4 + q;
            const int nsrc = csr_src[min(j, last)];
            const float nsc = (j < end) ? al_s[nsrc * HEADS + h] : -__builtin_inff();
            const short8 nv0 = *(const short8*)&h1[(size_t)nsrc * HD + fl * 16];
            const short8 nv1 = *(const short8*)&h1[(size_t)nsrc * HD + fl * 16 + 8];
            float e_ = sc + ad;
            e_ = e_ > 0.f ? e_ : NEG_SLOPE * e_;
            const float p = __expf(e_);
            s += p;
            #pragma unroll
            for (int k = 0; k < 8; ++k)
                acc[k] = fmaf(p, bf2f((unsigned short)v0[k]), acc[k]);
            #pragma unroll
            for (int k = 0; k < 8; ++k)
                acc[8 + k] = fmaf(p, bf2f((unsigned short)v1[k]), acc[8 + k]);
            sc = nsc; v0 = nv0; v1 = nv1;
        }
    }
    // combine the 4 edge streams (lanes with equal fl)
    s += __shfl_xor(s, 16);
    s += __shfl_xor(s, 32);
    #pragma unroll
    for (int k = 0; k < 16; ++k) {
        acc[k] += __shfl_xor(acc[k], 16);
        acc[k] += __shfl_xor(acc[k], 32);
    }

    if (q == 0) {
        const float inv = 1.f / (s + 1e-16f);
        float bb[16];
        *(float4*)&bb[0]  = *(const float4*)&b1[fl * 16];
        *(float4*)&bb[4]  = *(const float4*)&b1[fl * 16 + 4];
        *(float4*)&bb[8]  = *(const float4*)&b1[fl * 16 + 8];
        *(float4*)&bb[12] = *(const float4*)&b1[fl * 16 + 12];
        short8 ob0, ob1;
        #pragma unroll
        for (int k = 0; k < 8; ++k) {
            const float o0 = acc[k] * inv + bb[k];
            const float o1 = acc[8 + k] * inv + bb[8 + k];
            const float e0 = o0 > 0.f ? o0 : expm1f(o0);
            const float e1 = o1 > 0.f ? o1 : expm1f(o1);
            ob0[k] = (short)f2bf(e0);
            ob1[k] = (short)f2bf(e1);
        }
        *(short8*)&h_act[(size_t)node * HD + fl * 16] = ob0;
        *(short8*)&h_act[(size_t)node * HD + fl * 16 + 8] = ob1;
    }
}

// ---------------- GEMM2 via MFMA: h2[N,64] = h_act[N,256] @ W2pad + dots -----
#define G2M 64          // nodes per block (16 per wave)
#define BSTRIDE 264

__global__ __launch_bounds__(256) void gemm2_kernel(const unsigned short* __restrict__ h_act,
                                                    const unsigned short* __restrict__ W2t,
                                                    const float* __restrict__ a_s2,
                                                    const float* __restrict__ a_d2,
                                                    unsigned short* __restrict__ h2,
                                                    float* __restrict__ al_s,
                                                    float* __restrict__ al_d) {
    __shared__ unsigned short Bt[NCLSP][BSTRIDE];  // 33.8 KB
    const int tid = threadIdx.x;
    const int wave = tid >> 6;
    const int lane = tid & 63;
    const int quad = lane >> 4;
    const int col = lane & 15;
    const int m0 = blockIdx.x * G2M;

    #pragma unroll
    for (int it = 0; it < 8; ++it) {
        const int ch = it * 256 + tid;        // 0..2047
        const int n = ch >> 5;
        const int c8 = (ch & 31) * 8;
        *(uint4*)&Bt[n][c8] = *(const uint4*)&W2t[(size_t)n * HD + c8];
    }

    const int rowm = m0 + wave * 16 + col;
    const int arow = min(rowm, NNODES - 1);
    short8 af[8];
    #pragma unroll
    for (int ks = 0; ks < 8; ++ks)
        af[ks] = *(const short8*)&h_act[(size_t)arow * HD + ks * 32 + quad * 8];

    __syncthreads();

    f32x4 acc[4] = {};
    #pragma unroll
    for (int j = 0; j < 4; ++j) {
        #pragma unroll
        for (int ks = 0; ks < 8; ++ks) {
            const short8 bfr = *(const short8*)&Bt[j * 16 + col][ks * 32 + quad * 8];
            acc[j] = __builtin_amdgcn_mfma_f32_16x16x32_bf16(af[ks], bfr, acc[j], 0, 0, 0);
        }
    }

    float ps[4] = {0.f, 0.f, 0.f, 0.f};
    float pd[4] = {0.f, 0.f, 0.f, 0.f};
    #pragma unroll
    for (int j = 0; j < 4; ++j) {
        const int c = j * 16 + col;
        const bool cv = c < NCLS;
        const float asc = cv ? a_s2[c] : 0.f;
        const float adc = cv ? a_d2[c] : 0.f;
        #pragma unroll
        for (int reg = 0; reg < 4; ++reg) {
            const float v = acc[j][reg];
            ps[reg] += v * asc;
            pd[reg] += v * adc;
            const int node = m0 + wave * 16 + quad * 4 + reg;
            if (node < NNODES)
                h2[(size_t)node * NCLSP + c] = f2bf(v);   // pad cols write exact 0
        }
    }
    #pragma unroll
    for (int reg = 0; reg < 4; ++reg) {
        #pragma unroll
        for (int off = 1; off < 16; off <<= 1) {
            ps[reg] += __shfl_xor(ps[reg], off);
            pd[reg] += __shfl_xor(pd[reg], off);
        }
    }
    if (col == 0) {
        #pragma unroll
        for (int reg = 0; reg < 4; ++reg) {
            const int node = m0 + wave * 16 + quad * 4 + reg;
            if (node < NNODES) {
                al_s[node] = ps[reg];
                al_d[node] = pd[reg];
            }
        }
    }
}

// ---------------- layer-2 aggregation: octet-per-edge, 8 streams -------------
// h2 padded to 64 cols: 8 lanes x 16B (8 bf16 classes) per edge, 8 edges in
// flight per wave; deg/8 iterations instead of deg/2, 16B coalesced loads.
__global__ __launch_bounds__(256) void agg2_kernel(const unsigned short* __restrict__ h2,
                                                   const float* __restrict__ al_s,
                                                   const float* __restrict__ al_d,
                                                   const int* __restrict__ offsets,
                                                   const int* __restrict__ csr_src,
                                                   const float* __restrict__ b2,
                                                   float* __restrict__ out) {
    const int node = (blockIdx.x * 256 + threadIdx.x) >> 6;
    const int lane = threadIdx.x & 63;
    const int oct = lane >> 3;       // edge stream 0..7
    const int fl = lane & 7;         // classes fl*8 .. fl*8+7
    const float ad = al_d[node];
    const int start = offsets[node];
    const int end = offsets[node + 1];
    const int last = end - 1;

    float s = 0.f;
    float acc[8] = {};

    {
        const int idx = start + oct;
        const int src0 = csr_src[min(idx, last)];
        float sc = (idx < end) ? al_s[src0] : -__builtin_inff();
        short8 v = *(const short8*)&h2[(size_t)src0 * NCLSP + fl * 8];

        for (int i = start; i < end; i += 8) {
            const int j = i + 8 + oct;
            const int nsrc = csr_src[min(j, last)];
            const float nsc = (j < end) ? al_s[nsrc] : -__builtin_inff();
            const short8 nv = *(const short8*)&h2[(size_t)nsrc * NCLSP + fl * 8];
            float e_ = sc + ad;
            e_ = e_ > 0.f ? e_ : NEG_SLOPE * e_;
            const float p = __expf(e_);
            s += p;
            #pragma unroll
            for (int k = 0; k < 8; ++k)
                acc[k] = fmaf(p, bf2f((unsigned short)v[k]), acc[k]);
            sc = nsc; v = nv;
        }
    }
    // combine the 8 edge streams (lanes with equal fl)
    s += __shfl_xor(s, 8);
    s += __shfl_xor(s, 16);
    s += __shfl_xor(s, 32);
    #pragma unroll
    for (int k = 0; k < 8; ++k) {
        acc[k] += __shfl_xor(acc[k], 8);
        acc[k] += __shfl_xor(acc[k], 16);
        acc[k] += __shfl_xor(acc[k], 32);
    }

    if (oct == 0) {
        const float inv = 1.f / (s + 1e-16f);
        float o[8];
        float mx = -1e30f;
        #pragma unroll
        for (int k = 0; k < 8; ++k) {
            const int c = fl * 8 + k;
            const float bc = (c < NCLS) ? b2[c] : 0.f;
            o[k] = acc[k] * inv + bc;
            if (c < NCLS) mx = fmaxf(mx, o[k]);
        }
        #pragma unroll
        for (int off = 1; off < 8; off <<= 1) mx = fmaxf(mx, __shfl_xor(mx, off));
        float ex = 0.f;
        #pragma unroll
        for (int k = 0; k < 8; ++k) {
            const int c = fl * 8 + k;
            if (c < NCLS) ex += __expf(o[k] - mx);
        }
        #pragma unroll
        for (int off = 1; off < 8; off <<= 1) ex += __shfl_xor(ex, off);
        const float lse = mx + logf(ex);
        if (fl < 5) {
            float4 r0, r1;
            r0.x = o[0] - lse; r0.y = o[1] - lse; r0.z = o[2] - lse; r0.w = o[3] - lse;
            r1.x = o[4] - lse; r1.y = o[5] - lse; r1.z = o[6] - lse; r1.w = o[7] - lse;
            *(float4*)&out[(size_t)node * NCLS + fl * 8] = r0;
            *(float4*)&out[(size_t)node * NCLS + fl * 8 + 4] = r1;
        }
    }
}

// ---------------- launch -----------------------------------------------------
extern "C" void kernel_launch(void* const* d_in, const int* in_sizes, int n_in,
                              void* d_out, int out_size, void* d_ws, size_t ws_size,
                              hipStream_t stream) {
    const float* x      = (const float*)d_in[0];
    const int*   ei     = (const int*)d_in[1];
    const float* W1     = (const float*)d_in[2];
    const float* a_src1 = (const float*)d_in[3];
    const float* a_dst1 = (const float*)d_in[4];
    const float* b1     = (const float*)d_in[5];
    const float* W2     = (const float*)d_in[6];
    const float* a_src2 = (const float*)d_in[7];
    const float* a_dst2 = (const float*)d_in[8];
    const float* b2     = (const float*)d_in[9];
    float* out = (float*)d_out;
    const int E = in_sizes[1] / 2;

    char* ws = (char*)d_ws;
    size_t off = 0;
    auto alloc = [&](size_t bytes) -> char* {
        char* p = ws + off;
        off += (bytes + 255) & ~(size_t)255;
        return p;
    };
    unsigned short* xb    = (unsigned short*)alloc((size_t)NPAD * FIN * 2);
    unsigned short* W1t   = (unsigned short*)alloc((size_t)FIN * HD * 2);
    unsigned short* W2t   = (unsigned short*)alloc((size_t)NCLSP * HD * 2);
    unsigned short* h1    = (unsigned short*)alloc((size_t)NNODES * HD * 2);
    unsigned short* h_act = (unsigned short*)alloc((size_t)NNODES * HD * 2);
    unsigned short* h2    = (unsigned short*)alloc((size_t)NNODES * NCLSP * 2);
    float* al_s1  = (float*)alloc((size_t)NNODES * HEADS * 4);
    float* al_d1  = (float*)alloc((size_t)NNODES * HEADS * 4);
    float* al_s2  = (float*)alloc((size_t)NNODES * 4);
    float* al_d2  = (float*)alloc((size_t)NNODES * 4);
    int*   deg    = (int*)alloc((size_t)NNODES * 4);
    int*   psum   = (int*)alloc((size_t)NNODES * 4);
    int*   bsum   = (int*)alloc((size_t)SBLK * 4);
    int*   offs   = (int*)alloc((size_t)(NNODES + 1) * 4);
    int*   cursor = (int*)alloc((size_t)NNODES * 4);
    int*   csrsrc = (int*)alloc((size_t)E * 4);

    hipMemsetAsync(deg, 0, (size_t)NNODES * 4, stream);
    hipMemsetAsync(cursor, 0, (size_t)NNODES * 4, stream);

    const int eb = (E + 255) / 256;
    xcast_kernel<<<(int)((size_t)NPAD * FIN / 8 / 256), 256, 0, stream>>>(x, xb);
    w1t_kernel<<<FIN * HD / 256, 256, 0, stream>>>(W1, W1t);
    w2t_kernel<<<NCLSP, 256, 0, stream>>>(W2, W2t);
    deg_kernel<<<eb, 256, 0, stream>>>(ei, E, deg);
    scan1_kernel<<<NSCAN, SBLK, 0, stream>>>(deg, psum, bsum);
    scan2_kernel<<<1, SBLK, 0, stream>>>(bsum, offs);
    scan3_kernel<<<NSCAN, SBLK, 0, stream>>>(deg, psum, bsum, offs);
    scatter_kernel<<<eb, 256, 0, stream>>>(ei, E, offs, cursor, csrsrc);

    gemm1_kernel<<<NPAD / BM, 256, 0, stream>>>(xb, W1t, a_src1, a_dst1, h1, al_s1, al_d1);
    agg1_kernel<<<NNODES / 4, 256, 0, stream>>>(h1, al_s1, al_d1, offs, csrsrc, b1, h_act);
    gemm2_kernel<<<(NNODES + G2M - 1) / G2M, 256, 0, stream>>>(h_act, W2t, a_src2, a_dst2, h2, al_s2, al_d2);
    agg2_kernel<<<NNODES / 4, 256, 0, stream>>>(h2, al_s2, al_d2, offs, csrsrc, b2, out);
}

// Round 2
// 408.435 us; speedup vs baseline: 1.1163x; 1.0469x over previous
//
#include <hip/hip_runtime.h>
#include <math.h>

#define NNODES 50000
#define NPAD 50176         // padded rows for unguarded global_load_lds staging
#define FIN 512
#define HID 64
#define HEADS 4
#define HD (HEADS * HID)   // 256
#define NCLS 40
#define NCLSP 64           // padded to 4x16 MFMA n-tiles; pow2 for 8-lane-per-edge agg2
#define NEG_SLOPE 0.2f
#define SBLK 256
#define NSCAN ((NNODES + SBLK - 1) / SBLK)   // 196

#define XBBLK (NPAD * FIN / 8 / 256)         // 12544 xcast blocks
#define W1TBLK (FIN * HD / 256)              // 512
#define W2TBLK NCLSP                         // 64
#define DEGBASE (XBBLK + W1TBLK + W2TBLK)    // 13120

typedef __attribute__((ext_vector_type(8))) short short8;
typedef __attribute__((ext_vector_type(4))) float f32x4;

static __device__ inline unsigned short f2bf(float f) {
    unsigned int u = __builtin_bit_cast(unsigned int, f);
    unsigned int r = (u + 0x7FFFu + ((u >> 16) & 1u)) >> 16;
    return (unsigned short)r;
}
static __device__ inline float bf2f(unsigned short b) {
    return __builtin_bit_cast(float, (unsigned int)b << 16);
}
static __device__ inline void gload_lds16(const unsigned short* g, unsigned short* l) {
    __builtin_amdgcn_global_load_lds(
        (const __attribute__((address_space(1))) unsigned int*)g,
        (__attribute__((address_space(3))) unsigned int*)l, 16, 0, 0);
}

// ---------------- fused preprocess: xcast + W1t + W2t + deg + csr pad --------
__global__ __launch_bounds__(256) void pre_kernel(const float* __restrict__ x,
                                                  unsigned short* __restrict__ xb,
                                                  const float* __restrict__ W1,
                                                  unsigned short* __restrict__ W1t,
                                                  const float* __restrict__ W2,
                                                  unsigned short* __restrict__ W2t,
                                                  const int* __restrict__ ei, int E,
                                                  int* __restrict__ deg,
                                                  int* __restrict__ csr_pad) {
    const int b = blockIdx.x;
    const int tid = threadIdx.x;
    if (b < XBBLK) {
        const size_t idx = ((size_t)b * 256 + tid) * 8;
        if (idx < (size_t)NNODES * FIN) {
            const float4 v0 = *(const float4*)&x[idx];
            const float4 v1 = *(const float4*)&x[idx + 4];
            ushort4 p0, p1;
            p0.x = f2bf(v0.x); p0.y = f2bf(v0.y); p0.z = f2bf(v0.z); p0.w = f2bf(v0.w);
            p1.x = f2bf(v1.x); p1.y = f2bf(v1.y); p1.z = f2bf(v1.z); p1.w = f2bf(v1.w);
            *(ushort4*)&xb[idx] = p0;
            *(ushort4*)&xb[idx + 4] = p1;
        } else {
            const ushort4 z = {0, 0, 0, 0};
            *(ushort4*)&xb[idx] = z;
            *(ushort4*)&xb[idx + 4] = z;
        }
    } else if (b < XBBLK + W1TBLK) {
        const int idx = (b - XBBLK) * 256 + tid;
        const int k = idx >> 8;
        const int n = idx & 255;
        W1t[n * FIN + k] = f2bf(W1[idx]);
    } else if (b < DEGBASE) {
        const int idx = (b - XBBLK - W1TBLK) * 256 + tid;
        const int n = idx >> 8;
        const int k = idx & 255;
        W2t[n * HD + k] = (n < NCLS) ? f2bf(W2[k * NCLS + n]) : (unsigned short)0;
    } else {
        const int e = (b - DEGBASE) * 256 + tid;
        if (e < E) atomicAdd(&deg[ei[E + e]], 1);
        if (b == DEGBASE && tid < 64) csr_pad[tid] = 0;
    }
}

// ---------------- GEMM1: BM=64, BN=256, 2-phase double-buffered + fused al1 --
#define BM 64
#define BN 256
#define BK 32

__global__ __launch_bounds__(256) void gemm1_kernel(const unsigned short* __restrict__ xb,
                                                    const unsigned short* __restrict__ W1t,
                                                    const float* __restrict__ a_src,
                                                    const float* __restrict__ a_dst,
                                                    unsigned short* __restrict__ h1,
                                                    float* __restrict__ al_s,
                                                    float* __restrict__ al_d) {
    __shared__ unsigned short As[2][BM * BK];  // 2 x 4 KB
    __shared__ unsigned short Bs[2][BN * BK];  // 2 x 16 KB
    const int tid = threadIdx.x;
    const int wave = tid >> 6;
    const int lane = tid & 63;
    const int quad = lane >> 4;
    const int col = lane & 15;
    const int m0 = blockIdx.x * BM;
    const int srow = lane >> 2;
    const int skk = (lane & 3) * 8;

    f32x4 acc[4][4] = {};

    auto stage = [&](int buf, int k0) {
        const int r = wave * 16 + srow;
        gload_lds16(&xb[(size_t)(m0 + r) * FIN + k0 + skk], &As[buf][r * BK + skk]);
        #pragma unroll
        for (int c = 0; c < 4; ++c) {
            const int rr = c * 64 + wave * 16 + srow;
            gload_lds16(&W1t[(size_t)rr * FIN + k0 + skk], &Bs[buf][rr * BK + skk]);
        }
    };
    auto compute = [&](int buf) {
        short8 af[4], bfv[4];
        #pragma unroll
        for (int i = 0; i < 4; ++i)
            af[i] = *(const short8*)&As[buf][(i * 16 + col) * BK + quad * 8];
        #pragma unroll
        for (int j = 0; j < 4; ++j)
            bfv[j] = *(const short8*)&Bs[buf][(wave * 64 + j * 16 + col) * BK + quad * 8];
        #pragma unroll
        for (int i = 0; i < 4; ++i)
            #pragma unroll
            for (int j = 0; j < 4; ++j)
                acc[i][j] = __builtin_amdgcn_mfma_f32_16x16x32_bf16(af[i], bfv[j], acc[i][j], 0, 0, 0);
    };

    stage(0, 0);
    __syncthreads();
    int cur = 0;
    for (int k0 = BK; k0 < FIN; k0 += BK) {
        stage(cur ^ 1, k0);
        compute(cur);
        __syncthreads();
        cur ^= 1;
    }
    compute(cur);

    float asv[4], adv[4];
    #pragma unroll
    for (int j = 0; j < 4; ++j) {
        asv[j] = a_src[wave * 64 + j * 16 + col];
        adv[j] = a_dst[wave * 64 + j * 16 + col];
    }
    #pragma unroll
    for (int i = 0; i < 4; ++i) {
        #pragma unroll
        for (int reg = 0; reg < 4; ++reg) {
            const int row = i * 16 + quad * 4 + reg;
            const int gm = m0 + row;
            float ds = 0.f, dd = 0.f;
            #pragma unroll
            for (int j = 0; j < 4; ++j) {
                const float v = acc[i][j][reg];
                ds = fmaf(v, asv[j], ds);
                dd = fmaf(v, adv[j], dd);
                if (gm < NNODES) {
                    const int gc = wave * 64 + j * 16 + col;
                    h1[(size_t)gm * HD + gc] = f2bf(v);
                }
            }
            #pragma unroll
            for (int off = 1; off < 16; off <<= 1) {
                ds += __shfl_xor(ds, off);
                dd += __shfl_xor(dd, off);
            }
            if (col == 0 && gm < NNODES) {
                al_s[gm * HEADS + wave] = ds;
                al_d[gm * HEADS + wave] = dd;
            }
        }
    }
}

// ---------------- CSR build: scans ------------------------------------------
__global__ __launch_bounds__(SBLK) void scan1_kernel(const int* __restrict__ deg,
                                                     int* __restrict__ psum,
                                                     int* __restrict__ bsum) {
    __shared__ int ws[4];
    const int t = threadIdx.x;
    const int idx = blockIdx.x * SBLK + t;
    const int lane = t & 63;
    const int w = t >> 6;
    int sv = (idx < NNODES) ? deg[idx] : 0;
    #pragma unroll
    for (int off = 1; off < 64; off <<= 1) {
        const int n = __shfl_up(sv, off);
        if (lane >= off) sv += n;
    }
    if (lane == 63) ws[w] = sv;
    __syncthreads();
    int add = 0;
    for (int i = 0; i < w; ++i) add += ws[i];
    sv += add;
    if (idx < NNODES) psum[idx] = sv;
    if (t == SBLK - 1) bsum[blockIdx.x] = sv;
}

__global__ __launch_bounds__(SBLK) void scan23_kernel(const int* __restrict__ deg,
                                                      const int* __restrict__ psum,
                                                      const int* __restrict__ bsum,
                                                      int* __restrict__ offsets) {
    __shared__ int ws[4];
    __shared__ int sc[NSCAN];
    const int t = threadIdx.x;
    const int lane = t & 63;
    const int w = t >> 6;
    int sv = (t < NSCAN) ? bsum[t] : 0;
    #pragma unroll
    for (int off = 1; off < 64; off <<= 1) {
        const int n = __shfl_up(sv, off);
        if (lane >= off) sv += n;
    }
    if (lane == 63) ws[w] = sv;
    __syncthreads();
    int add = 0;
    for (int i = 0; i < w; ++i) add += ws[i];
    sv += add;
    if (t < NSCAN) sc[t] = sv;
    __syncthreads();
    const int idx = blockIdx.x * SBLK + t;
    const int boff = (blockIdx.x > 0) ? sc[blockIdx.x - 1] : 0;
    if (idx < NNODES) offsets[idx] = psum[idx] - deg[idx] + boff;
    if (blockIdx.x == 0 && t == 0) offsets[NNODES] = sc[NSCAN - 1];
}

__global__ void scatter_kernel(const int* __restrict__ ei, int E,
                               const int* __restrict__ offsets,
                               int* __restrict__ cursor,
                               int* __restrict__ csr_src) {
    const int e = blockIdx.x * 256 + threadIdx.x;
    if (e < E) {
        const int dst = ei[E + e];
        const int src = ei[e];
        const int pos = offsets[dst] + atomicAdd(&cursor[dst], 1);
        csr_src[pos] = src;
    }
}

// ---------------- layer-1 aggregation: quarter-wave-per-edge, 4 streams ------
__global__ __launch_bounds__(256) void agg1_kernel(const unsigned short* __restrict__ h1,
                                                   const float* __restrict__ al_s,
                                                   const float* __restrict__ al_d,
                                                   const int* __restrict__ offsets,
                                                   const int* __restrict__ csr_src,
                                                   const float* __restrict__ b1,
                                                   unsigned short* __restrict__ h_act) {
    const int node = (blockIdx.x * 256 + threadIdx.x) >> 6;
    const int lane = threadIdx.x & 63;
    const int q = lane >> 4;
    const int fl = lane & 15;
    const int h = fl >> 2;
    const float ad = al_d[node * HEADS + h];
    const int start = offsets[node];
    const int end = offsets[node + 1];

    float s = 0.f;
    float acc[16] = {};

    {
        const int idx = start + q;
        const int src0 = csr_src[idx];
        float sc = (idx < end) ? al_s[src0 * HEADS + h] : -__builtin_inff();
        short8 v0 = *(const short8*)&h1[(size_t)src0 * HD + fl * 16];
        short8 v1 = *(const short8*)&h1[(size_t)src0 * HD + fl * 16 + 8];

        for (int i = start; i < end; i += 4) {
            const int j = i + 4 + q;
            const int nsrc = csr_src[j];
            const float nsc = (j < end) ? al_s[nsrc * HEADS + h] : -__builtin_inff();
            const short8 nv0 = *(const short8*)&h1[(size_t)nsrc * HD + fl * 16];
            const short8 nv1 = *(const short8*)&h1[(size_t)nsrc * HD + fl * 16 + 8];
            float e_ = sc + ad;
            e_ = e_ > 0.f ? e_ : NEG_SLOPE * e_;
            const float p = __expf(e_);
            s += p;
            #pragma unroll
            for (int k = 0; k < 8; ++k)
                acc[k] = fmaf(p, bf2f((unsigned short)v0[k]), acc[k]);
            #pragma unroll
            for (int k = 0; k < 8; ++k)
                acc[8 + k] = fmaf(p, bf2f((unsigned short)v1[k]), acc[8 + k]);
            sc = nsc; v0 = nv0; v1 = nv1;
        }
    }
    s += __shfl_xor(s, 16);
    s += __shfl_xor(s, 32);
    #pragma unroll
    for (int k = 0; k < 16; ++k) {
        acc[k] += __shfl_xor(acc[k], 16);
        acc[k] += __shfl_xor(acc[k], 32);
    }

    if (q == 0) {
        const float inv = 1.f / (s + 1e-16f);
        float bb[16];
        *(float4*)&bb[0]  = *(const float4*)&b1[fl * 16];
        *(float4*)&bb[4]  = *(const float4*)&b1[fl * 16 + 4];
        *(float4*)&bb[8]  = *(const float4*)&b1[fl * 16 + 8];
        *(float4*)&bb[12] = *(const float4*)&b1[fl * 16 + 12];
        short8 ob0, ob1;
        #pragma unroll
        for (int k = 0; k < 8; ++k) {
            const float o0 = acc[k] * inv + bb[k];
            const float o1 = acc[8 + k] * inv + bb[8 + k];
            const float e0 = o0 > 0.f ? o0 : expm1f(o0);
            const float e1 = o1 > 0.f ? o1 : expm1f(o1);
            ob0[k] = (short)f2bf(e0);
            ob1[k] = (short)f2bf(e1);
        }
        *(short8*)&h_act[(size_t)node * HD + fl * 16] = ob0;
        *(short8*)&h_act[(size_t)node * HD + fl * 16 + 8] = ob1;
    }
}

// ---------------- GEMM2 via MFMA: h2[N,64] = h_act[N,256] @ W2pad + dots -----
#define G2M 64
#define BSTRIDE 264

__global__ __launch_bounds__(256) void gemm2_kernel(const unsigned short* __restrict__ h_act,
                                                    const unsigned short* __restrict__ W2t,
                                                    const float* __restrict__ a_s2,
                                                    const float* __restrict__ a_d2,
                                                    unsigned short* __restrict__ h2,
                                                    float* __restrict__ al_s,
                                                    float* __restrict__ al_d) {
    __shared__ unsigned short Bt[NCLSP][BSTRIDE];
    const int tid = threadIdx.x;
    const int wave = tid >> 6;
    const int lane = tid & 63;
    const int quad = lane >> 4;
    const int col = lane & 15;
    const int m0 = blockIdx.x * G2M;

    #pragma unroll
    for (int it = 0; it < 8; ++it) {
        const int ch = it * 256 + tid;
        const int n = ch >> 5;
        const int c8 = (ch & 31) * 8;
        *(uint4*)&Bt[n][c8] = *(const uint4*)&W2t[(size_t)n * HD + c8];
    }

    const int rowm = m0 + wave * 16 + col;
    const int arow = min(rowm, NNODES - 1);
    short8 af[8];
    #pragma unroll
    for (int ks = 0; ks < 8; ++ks)
        af[ks] = *(const short8*)&h_act[(size_t)arow * HD + ks * 32 + quad * 8];

    __syncthreads();

    f32x4 acc[4] = {};
    #pragma unroll
    for (int j = 0; j < 4; ++j) {
        #pragma unroll
        for (int ks = 0; ks < 8; ++ks) {
            const short8 bfr = *(const short8*)&Bt[j * 16 + col][ks * 32 + quad * 8];
            acc[j] = __builtin_amdgcn_mfma_f32_16x16x32_bf16(af[ks], bfr, acc[j], 0, 0, 0);
        }
    }

    float ps[4] = {0.f, 0.f, 0.f, 0.f};
    float pd[4] = {0.f, 0.f, 0.f, 0.f};
    #pragma unroll
    for (int j = 0; j < 4; ++j) {
        const int c = j * 16 + col;
        const bool cv = c < NCLS;
        const float asc = cv ? a_s2[c] : 0.f;
        const float adc = cv ? a_d2[c] : 0.f;
        #pragma unroll
        for (int reg = 0; reg < 4; ++reg) {
            const float v = acc[j][reg];
            ps[reg] += v * asc;
            pd[reg] += v * adc;
            const int node = m0 + wave * 16 + quad * 4 + reg;
            if (node < NNODES)
                h2[(size_t)node * NCLSP + c] = f2bf(v);
        }
    }
    #pragma unroll
    for (int reg = 0; reg < 4; ++reg) {
        #pragma unroll
        for (int off = 1; off < 16; off <<= 1) {
            ps[reg] += __shfl_xor(ps[reg], off);
            pd[reg] += __shfl_xor(pd[reg], off);
        }
    }
    if (col == 0) {
        #pragma unroll
        for (int reg = 0; reg < 4; ++reg) {
            const int node = m0 + wave * 16 + quad * 4 + reg;
            if (node < NNODES) {
                al_s[node] = ps[reg];
                al_d[node] = pd[reg];
            }
        }
    }
}

// ---------------- layer-2 aggregation: octet-per-edge, 8 streams -------------
__global__ __launch_bounds__(256) void agg2_kernel(const unsigned short* __restrict__ h2,
                                                   const float* __restrict__ al_s,
                                                   const float* __restrict__ al_d,
                                                   const int* __restrict__ offsets,
                                                   const int* __restrict__ csr_src,
                                                   const float* __restrict__ b2,
                                                   float* __restrict__ out) {
    const int node = (blockIdx.x * 256 + threadIdx.x) >> 6;
    const int lane = threadIdx.x & 63;
    const int oct = lane >> 3;
    const int fl = lane & 7;
    const float ad = al_d[node];
    const int start = offsets[node];
    const int end = offsets[node + 1];

    float s = 0.f;
    float acc[8] = {};

    {
        const int idx = start + oct;
        const int src0 = csr_src[idx];
        float sc = (idx < end) ? al_s[src0] : -__builtin_inff();
        short8 v = *(const short8*)&h2[(size_t)src0 * NCLSP + fl * 8];

        for (int i = start; i < end; i += 8) {
            const int j = i + 8 + oct;
            const int nsrc = csr_src[j];
            const float nsc = (j < end) ? al_s[nsrc] : -__builtin_inff();
            const short8 nv = *(const short8*)&h2[(size_t)nsrc * NCLSP + fl * 8];
            float e_ = sc + ad;
            e_ = e_ > 0.f ? e_ : NEG_SLOPE * e_;
            const float p = __expf(e_);
            s += p;
            #pragma unroll
            for (int k = 0; k < 8; ++k)
                acc[k] = fmaf(p, bf2f((unsigned short)v[k]), acc[k]);
            sc = nsc; v = nv;
        }
    }
    s += __shfl_xor(s, 8);
    s += __shfl_xor(s, 16);
    s += __shfl_xor(s, 32);
    #pragma unroll
    for (int k = 0; k < 8; ++k) {
        acc[k] += __shfl_xor(acc[k], 8);
        acc[k] += __shfl_xor(acc[k], 16);
        acc[k] += __shfl_xor(acc[k], 32);
    }

    if (oct == 0) {
        const float inv = 1.f / (s + 1e-16f);
        float o[8];
        float mx = -1e30f;
        #pragma unroll
        for (int k = 0; k < 8; ++k) {
            const int c = fl * 8 + k;
            const float bc = (c < NCLS) ? b2[c] : 0.f;
            o[k] = acc[k] * inv + bc;
            if (c < NCLS) mx = fmaxf(mx, o[k]);
        }
        #pragma unroll
        for (int off = 1; off < 8; off <<= 1) mx = fmaxf(mx, __shfl_xor(mx, off));
        float ex = 0.f;
        #pragma unroll
        for (int k = 0; k < 8; ++k) {
            const int c = fl * 8 + k;
            if (c < NCLS) ex += __expf(o[k] - mx);
        }
        #pragma unroll
        for (int off = 1; off < 8; off <<= 1) ex += __shfl_xor(ex, off);
        const float lse = mx + logf(ex);
        if (fl < 5) {
            float4 r0, r1;
            r0.x = o[0] - lse; r0.y = o[1] - lse; r0.z = o[2] - lse; r0.w = o[3] - lse;
            r1.x = o[4] - lse; r1.y = o[5] - lse; r1.z = o[6] - lse; r1.w = o[7] - lse;
            *(float4*)&out[(size_t)node * NCLS + fl * 8] = r0;
            *(float4*)&out[(size_t)node * NCLS + fl * 8 + 4] = r1;
        }
    }
}

// ---------------- launch: 9 dispatches (was 15) ------------------------------
extern "C" void kernel_launch(void* const* d_in, const int* in_sizes, int n_in,
                              void* d_out, int out_size, void* d_ws, size_t ws_size,
                              hipStream_t stream) {
    const float* x      = (const float*)d_in[0];
    const int*   ei     = (const int*)d_in[1];
    const float* W1     = (const float*)d_in[2];
    const float* a_src1 = (const float*)d_in[3];
    const float* a_dst1 = (const float*)d_in[4];
    const float* b1     = (const float*)d_in[5];
    const float* W2     = (const float*)d_in[6];
    const float* a_src2 = (const float*)d_in[7];
    const float* a_dst2 = (const float*)d_in[8];
    const float* b2     = (const float*)d_in[9];
    float* out = (float*)d_out;
    const int E = in_sizes[1] / 2;

    char* ws = (char*)d_ws;
    size_t off = 0;
    auto alloc = [&](size_t bytes) -> char* {
        char* p = ws + off;
        off += (bytes + 255) & ~(size_t)255;
        return p;
    };
    unsigned short* xb    = (unsigned short*)alloc((size_t)NPAD * FIN * 2);
    unsigned short* W1t   = (unsigned short*)alloc((size_t)FIN * HD * 2);
    unsigned short* W2t   = (unsigned short*)alloc((size_t)NCLSP * HD * 2);
    unsigned short* h1    = (unsigned short*)alloc((size_t)NNODES * HD * 2);
    unsigned short* h_act = (unsigned short*)alloc((size_t)NNODES * HD * 2);
    unsigned short* h2    = (unsigned short*)alloc((size_t)NNODES * NCLSP * 2);
    float* al_s1  = (float*)alloc((size_t)NNODES * HEADS * 4);
    float* al_d1  = (float*)alloc((size_t)NNODES * HEADS * 4);
    float* al_s2  = (float*)alloc((size_t)NNODES * 4);
    float* al_d2  = (float*)alloc((size_t)NNODES * 4);
    int*   deg    = (int*)alloc((size_t)NNODES * 4);   // adjacent to cursor:
    int*   cursor = (int*)alloc((size_t)NNODES * 4);   // one memset covers both
    int*   psum   = (int*)alloc((size_t)NNODES * 4);
    int*   bsum   = (int*)alloc((size_t)SBLK * 4);
    int*   offs   = (int*)alloc((size_t)(NNODES + 1) * 4);
    int*   csrsrc = (int*)alloc((size_t)E * 4 + 256);  // +64 safe pad entries

    const size_t degpad = ((size_t)NNODES * 4 + 255) & ~(size_t)255;
    hipMemsetAsync(deg, 0, degpad + (size_t)NNODES * 4, stream);

    const int eb = (E + 255) / 256;
    pre_kernel<<<DEGBASE + eb, 256, 0, stream>>>(x, xb, W1, W1t, W2, W2t, ei, E, deg, csrsrc + E);
    scan1_kernel<<<NSCAN, SBLK, 0, stream>>>(deg, psum, bsum);
    scan23_kernel<<<NSCAN, SBLK, 0, stream>>>(deg, psum, bsum, offs);
    scatter_kernel<<<eb, 256, 0, stream>>>(ei, E, offs, cursor, csrsrc);

    gemm1_kernel<<<NPAD / BM, 256, 0, stream>>>(xb, W1t, a_src1, a_dst1, h1, al_s1, al_d1);
    agg1_kernel<<<NNODES / 4, 256, 0, stream>>>(h1, al_s1, al_d1, offs, csrsrc, b1, h_act);
    gemm2_kernel<<<(NNODES + G2M - 1) / G2M, 256, 0, stream>>>(h_act, W2t, a_src2, a_dst2, h2, al_s2, al_d2);
    agg2_kernel<<<NNODES / 4, 256, 0, stream>>>(h2, al_s2, al_d2, offs, csrsrc, b2, out);
}

// Round 3
// 405.814 us; speedup vs baseline: 1.1235x; 1.0065x over previous
//
#include <hip/hip_runtime.h>
#include <math.h>

#define NNODES 50000
#define FIN 512
#define HID 64
#define HEADS 4
#define HD (HEADS * HID)   // 256
#define NCLS 40
#define NCLSP 64           // padded to 4x16 MFMA n-tiles; pow2 for 8-lane-per-edge agg2
#define NEG_SLOPE 0.2f
#define SBLK 256
#define NSCAN ((NNODES + SBLK - 1) / SBLK)   // 196

#define W1TBLK (FIN * HD / 256)              // 512
#define W2TBLK NCLSP                         // 64

typedef __attribute__((ext_vector_type(8))) short short8;
typedef __attribute__((ext_vector_type(4))) float f32x4;

static __device__ inline unsigned short f2bf(float f) {
    unsigned int u = __builtin_bit_cast(unsigned int, f);
    unsigned int r = (u + 0x7FFFu + ((u >> 16) & 1u)) >> 16;
    return (unsigned short)r;
}
static __device__ inline float bf2f(unsigned short b) {
    return __builtin_bit_cast(float, (unsigned int)b << 16);
}
static __device__ inline void gload_lds16(const unsigned short* g, unsigned short* l) {
    __builtin_amdgcn_global_load_lds(
        (const __attribute__((address_space(1))) unsigned int*)g,
        (__attribute__((address_space(3))) unsigned int*)l, 16, 0, 0);
}

// ---------------- preprocess: deg count + csr pad + W1t + W2t ----------------
// (xcast eliminated: fp32->bf16 cast of x fused into gemm1 A-staging)
__global__ __launch_bounds__(256) void pre_kernel(const float* __restrict__ W1,
                                                  unsigned short* __restrict__ W1t,
                                                  const float* __restrict__ W2,
                                                  unsigned short* __restrict__ W2t,
                                                  const int* __restrict__ ei, int E, int eb,
                                                  int* __restrict__ deg,
                                                  int* __restrict__ csr_pad) {
    const int b = blockIdx.x;
    const int tid = threadIdx.x;
    if (b < eb) {
        const int e = b * 256 + tid;
        if (e < E) atomicAdd(&deg[ei[E + e]], 1);
        if (b == 0 && tid < 64) csr_pad[tid] = 0;   // safe pad for clamp-free agg loops
    } else if (b < eb + W1TBLK) {
        // W1[512,256] fp32 -> W1t[256,512] bf16 (one k-column per block)
        const int idx = (b - eb) * 256 + tid;
        const int k = idx >> 8;
        const int n = idx & 255;
        W1t[n * FIN + k] = f2bf(W1[idx]);
    } else {
        // W2[256,40] fp32 -> W2t[64][256] bf16, rows 40..63 zero
        const int idx = (b - eb - W1TBLK) * 256 + tid;
        const int n = idx >> 8;
        const int k = idx & 255;
        W2t[n * HD + k] = (n < NCLS) ? f2bf(W2[k * NCLS + n]) : (unsigned short)0;
    }
}

// ---------------- GEMM1: BM=64, BN=256, double-buffered, fused x-cast + al1 --
// A-tile: x read fp32 -> reg convert -> ds_write (no xb intermediate).
// B-tile: W1t via global_load_lds DMA. One __syncthreads per K-step.
#define BM 64
#define BN 256
#define BK 32
#define G1BLK ((NNODES + BM - 1) / BM)   // 782

__global__ __launch_bounds__(256) void gemm1_kernel(const float* __restrict__ x,
                                                    const unsigned short* __restrict__ W1t,
                                                    const float* __restrict__ a_src,
                                                    const float* __restrict__ a_dst,
                                                    unsigned short* __restrict__ h1,
                                                    float* __restrict__ al_s,
                                                    float* __restrict__ al_d) {
    __shared__ unsigned short As[2][BM * BK];  // 2 x 4 KB
    __shared__ unsigned short Bs[2][BN * BK];  // 2 x 16 KB
    const int tid = threadIdx.x;
    const int wave = tid >> 6;
    const int lane = tid & 63;
    const int quad = lane >> 4;
    const int col = lane & 15;
    const int m0 = blockIdx.x * BM;
    const int srow = lane >> 2;          // 0..15 within a 16-row group
    const int skk = (lane & 3) * 8;      // 8-elem k-chunk

    // A source row, clamped: OOB rows load real (finite) data whose outputs
    // are discarded by the gm < NNODES guard in the epilogue.
    const int ar = wave * 16 + srow;                 // 0..63 LDS row
    const size_t agr = (size_t)min(m0 + ar, NNODES - 1) * FIN;

    f32x4 acc[4][4] = {};

    auto stageB = [&](int buf, int k0) {
        #pragma unroll
        for (int c = 0; c < 4; ++c) {
            const int rr = c * 64 + wave * 16 + srow;
            gload_lds16(&W1t[(size_t)rr * FIN + k0 + skk], &Bs[buf][rr * BK + skk]);
        }
    };
    auto stageA = [&](int buf, int k0) {
        const float4 v0 = *(const float4*)&x[agr + k0 + skk];
        const float4 v1 = *(const float4*)&x[agr + k0 + skk + 4];
        short8 p;
        p[0] = (short)f2bf(v0.x); p[1] = (short)f2bf(v0.y);
        p[2] = (short)f2bf(v0.z); p[3] = (short)f2bf(v0.w);
        p[4] = (short)f2bf(v1.x); p[5] = (short)f2bf(v1.y);
        p[6] = (short)f2bf(v1.z); p[7] = (short)f2bf(v1.w);
        *(short8*)&As[buf][ar * BK + skk] = p;
    };
    auto compute = [&](int buf) {
        short8 af[4], bfv[4];
        #pragma unroll
        for (int i = 0; i < 4; ++i)
            af[i] = *(const short8*)&As[buf][(i * 16 + col) * BK + quad * 8];
        #pragma unroll
        for (int j = 0; j < 4; ++j)
            bfv[j] = *(const short8*)&Bs[buf][(wave * 64 + j * 16 + col) * BK + quad * 8];
        #pragma unroll
        for (int i = 0; i < 4; ++i)
            #pragma unroll
            for (int j = 0; j < 4; ++j)
                acc[i][j] = __builtin_amdgcn_mfma_f32_16x16x32_bf16(af[i], bfv[j], acc[i][j], 0, 0, 0);
    };

    stageB(0, 0);
    stageA(0, 0);
    __syncthreads();
    int cur = 0;
    for (int k0 = BK; k0 < FIN; k0 += BK) {
        stageB(cur ^ 1, k0);   // async DMA flies under A-convert + compute
        stageA(cur ^ 1, k0);
        compute(cur);
        __syncthreads();
        cur ^= 1;
    }
    compute(cur);

    // epilogue: h1 write + fused per-head attention score dots (head == wave)
    float asv[4], adv[4];
    #pragma unroll
    for (int j = 0; j < 4; ++j) {
        asv[j] = a_src[wave * 64 + j * 16 + col];
        adv[j] = a_dst[wave * 64 + j * 16 + col];
    }
    #pragma unroll
    for (int i = 0; i < 4; ++i) {
        #pragma unroll
        for (int reg = 0; reg < 4; ++reg) {
            const int row = i * 16 + quad * 4 + reg;
            const int gm = m0 + row;
            float ds = 0.f, dd = 0.f;
            #pragma unroll
            for (int j = 0; j < 4; ++j) {
                const float v = acc[i][j][reg];
                ds = fmaf(v, asv[j], ds);
                dd = fmaf(v, adv[j], dd);
                if (gm < NNODES) {
                    const int gc = wave * 64 + j * 16 + col;
                    h1[(size_t)gm * HD + gc] = f2bf(v);
                }
            }
            #pragma unroll
            for (int off = 1; off < 16; off <<= 1) {
                ds += __shfl_xor(ds, off);
                dd += __shfl_xor(dd, off);
            }
            if (col == 0 && gm < NNODES) {
                al_s[gm * HEADS + wave] = ds;
                al_d[gm * HEADS + wave] = dd;
            }
        }
    }
}

// ---------------- CSR build: scans ------------------------------------------
__global__ __launch_bounds__(SBLK) void scan1_kernel(const int* __restrict__ deg,
                                                     int* __restrict__ psum,
                                                     int* __restrict__ bsum) {
    __shared__ int ws[4];
    const int t = threadIdx.x;
    const int idx = blockIdx.x * SBLK + t;
    const int lane = t & 63;
    const int w = t >> 6;
    int sv = (idx < NNODES) ? deg[idx] : 0;
    #pragma unroll
    for (int off = 1; off < 64; off <<= 1) {
        const int n = __shfl_up(sv, off);
        if (lane >= off) sv += n;
    }
    if (lane == 63) ws[w] = sv;
    __syncthreads();
    int add = 0;
    for (int i = 0; i < w; ++i) add += ws[i];
    sv += add;
    if (idx < NNODES) psum[idx] = sv;
    if (t == SBLK - 1) bsum[blockIdx.x] = sv;
}

__global__ __launch_bounds__(SBLK) void scan23_kernel(const int* __restrict__ deg,
                                                      const int* __restrict__ psum,
                                                      const int* __restrict__ bsum,
                                                      int* __restrict__ offsets) {
    __shared__ int ws[4];
    __shared__ int sc[NSCAN];
    const int t = threadIdx.x;
    const int lane = t & 63;
    const int w = t >> 6;
    int sv = (t < NSCAN) ? bsum[t] : 0;
    #pragma unroll
    for (int off = 1; off < 64; off <<= 1) {
        const int n = __shfl_up(sv, off);
        if (lane >= off) sv += n;
    }
    if (lane == 63) ws[w] = sv;
    __syncthreads();
    int add = 0;
    for (int i = 0; i < w; ++i) add += ws[i];
    sv += add;
    if (t < NSCAN) sc[t] = sv;
    __syncthreads();
    const int idx = blockIdx.x * SBLK + t;
    const int boff = (blockIdx.x > 0) ? sc[blockIdx.x - 1] : 0;
    if (idx < NNODES) offsets[idx] = psum[idx] - deg[idx] + boff;
    if (blockIdx.x == 0 && t == 0) offsets[NNODES] = sc[NSCAN - 1];
}

__global__ void scatter_kernel(const int* __restrict__ ei, int E,
                               const int* __restrict__ offsets,
                               int* __restrict__ cursor,
                               int* __restrict__ csr_src) {
    const int e = blockIdx.x * 256 + threadIdx.x;
    if (e < E) {
        const int dst = ei[E + e];
        const int src = ei[e];
        const int pos = offsets[dst] + atomicAdd(&cursor[dst], 1);
        csr_src[pos] = src;
    }
}

// ---------------- layer-1 aggregation: quarter-wave-per-edge, 4 streams ------
__global__ __launch_bounds__(256) void agg1_kernel(const unsigned short* __restrict__ h1,
                                                   const float* __restrict__ al_s,
                                                   const float* __restrict__ al_d,
                                                   const int* __restrict__ offsets,
                                                   const int* __restrict__ csr_src,
                                                   const float* __restrict__ b1,
                                                   unsigned short* __restrict__ h_act) {
    const int node = (blockIdx.x * 256 + threadIdx.x) >> 6;
    const int lane = threadIdx.x & 63;
    const int q = lane >> 4;
    const int fl = lane & 15;
    const int h = fl >> 2;
    const float ad = al_d[node * HEADS + h];
    const int start = offsets[node];
    const int end = offsets[node + 1];

    float s = 0.f;
    float acc[16] = {};

    {
        const int idx = start + q;
        const int src0 = csr_src[idx];
        float sc = (idx < end) ? al_s[src0 * HEADS + h] : -__builtin_inff();
        short8 v0 = *(const short8*)&h1[(size_t)src0 * HD + fl * 16];
        short8 v1 = *(const short8*)&h1[(size_t)src0 * HD + fl * 16 + 8];

        for (int i = start; i < end; i += 4) {
            const int j = i + 4 + q;
            const int nsrc = csr_src[j];
            const float nsc = (j < end) ? al_s[nsrc * HEADS + h] : -__builtin_inff();
            const short8 nv0 = *(const short8*)&h1[(size_t)nsrc * HD + fl * 16];
            const short8 nv1 = *(const short8*)&h1[(size_t)nsrc * HD + fl * 16 + 8];
            float e_ = sc + ad;
            e_ = e_ > 0.f ? e_ : NEG_SLOPE * e_;
            const float p = __expf(e_);
            s += p;
            #pragma unroll
            for (int k = 0; k < 8; ++k)
                acc[k] = fmaf(p, bf2f((unsigned short)v0[k]), acc[k]);
            #pragma unroll
            for (int k = 0; k < 8; ++k)
                acc[8 + k] = fmaf(p, bf2f((unsigned short)v1[k]), acc[8 + k]);
            sc = nsc; v0 = nv0; v1 = nv1;
        }
    }
    s += __shfl_xor(s, 16);
    s += __shfl_xor(s, 32);
    #pragma unroll
    for (int k = 0; k < 16; ++k) {
        acc[k] += __shfl_xor(acc[k], 16);
        acc[k] += __shfl_xor(acc[k], 32);
    }

    if (q == 0) {
        const float inv = 1.f / (s + 1e-16f);
        float bb[16];
        *(float4*)&bb[0]  = *(const float4*)&b1[fl * 16];
        *(float4*)&bb[4]  = *(const float4*)&b1[fl * 16 + 4];
        *(float4*)&bb[8]  = *(const float4*)&b1[fl * 16 + 8];
        *(float4*)&bb[12] = *(const float4*)&b1[fl * 16 + 12];
        short8 ob0, ob1;
        #pragma unroll
        for (int k = 0; k < 8; ++k) {
            const float o0 = acc[k] * inv + bb[k];
            const float o1 = acc[8 + k] * inv + bb[8 + k];
            const float e0 = o0 > 0.f ? o0 : expm1f(o0);
            const float e1 = o1 > 0.f ? o1 : expm1f(o1);
            ob0[k] = (short)f2bf(e0);
            ob1[k] = (short)f2bf(e1);
        }
        *(short8*)&h_act[(size_t)node * HD + fl * 16] = ob0;
        *(short8*)&h_act[(size_t)node * HD + fl * 16 + 8] = ob1;
    }
}

// ---------------- GEMM2 via MFMA: h2[N,64] = h_act[N,256] @ W2pad + dots -----
#define G2M 64
#define BSTRIDE 264

__global__ __launch_bounds__(256) void gemm2_kernel(const unsigned short* __restrict__ h_act,
                                                    const unsigned short* __restrict__ W2t,
                                                    const float* __restrict__ a_s2,
                                                    const float* __restrict__ a_d2,
                                                    unsigned short* __restrict__ h2,
                                                    float* __restrict__ al_s,
                                                    float* __restrict__ al_d) {
    __shared__ unsigned short Bt[NCLSP][BSTRIDE];
    const int tid = threadIdx.x;
    const int wave = tid >> 6;
    const int lane = tid & 63;
    const int quad = lane >> 4;
    const int col = lane & 15;
    const int m0 = blockIdx.x * G2M;

    #pragma unroll
    for (int it = 0; it < 8; ++it) {
        const int ch = it * 256 + tid;
        const int n = ch >> 5;
        const int c8 = (ch & 31) * 8;
        *(uint4*)&Bt[n][c8] = *(const uint4*)&W2t[(size_t)n * HD + c8];
    }

    const int rowm = m0 + wave * 16 + col;
    const int arow = min(rowm, NNODES - 1);
    short8 af[8];
    #pragma unroll
    for (int ks = 0; ks < 8; ++ks)
        af[ks] = *(const short8*)&h_act[(size_t)arow * HD + ks * 32 + quad * 8];

    __syncthreads();

    f32x4 acc[4] = {};
    #pragma unroll
    for (int j = 0; j < 4; ++j) {
        #pragma unroll
        for (int ks = 0; ks < 8; ++ks) {
            const short8 bfr = *(const short8*)&Bt[j * 16 + col][ks * 32 + quad * 8];
            acc[j] = __builtin_amdgcn_mfma_f32_16x16x32_bf16(af[ks], bfr, acc[j], 0, 0, 0);
        }
    }

    float ps[4] = {0.f, 0.f, 0.f, 0.f};
    float pd[4] = {0.f, 0.f, 0.f, 0.f};
    #pragma unroll
    for (int j = 0; j < 4; ++j) {
        const int c = j * 16 + col;
        const bool cv = c < NCLS;
        const float asc = cv ? a_s2[c] : 0.f;
        const float adc = cv ? a_d2[c] : 0.f;
        #pragma unroll
        for (int reg = 0; reg < 4; ++reg) {
            const float v = acc[j][reg];
            ps[reg] += v * asc;
            pd[reg] += v * adc;
            const int node = m0 + wave * 16 + quad * 4 + reg;
            if (node < NNODES)
                h2[(size_t)node * NCLSP + c] = f2bf(v);
        }
    }
    #pragma unroll
    for (int reg = 0; reg < 4; ++reg) {
        #pragma unroll
        for (int off = 1; off < 16; off <<= 1) {
            ps[reg] += __shfl_xor(ps[reg], off);
            pd[reg] += __shfl_xor(pd[reg], off);
        }
    }
    if (col == 0) {
        #pragma unroll
        for (int reg = 0; reg < 4; ++reg) {
            const int node = m0 + wave * 16 + quad * 4 + reg;
            if (node < NNODES) {
                al_s[node] = ps[reg];
                al_d[node] = pd[reg];
            }
        }
    }
}

// ---------------- layer-2 aggregation: octet-per-edge, 8 streams -------------
__global__ __launch_bounds__(256) void agg2_kernel(const unsigned short* __restrict__ h2,
                                                   const float* __restrict__ al_s,
                                                   const float* __restrict__ al_d,
                                                   const int* __restrict__ offsets,
                                                   const int* __restrict__ csr_src,
                                                   const float* __restrict__ b2,
                                                   float* __restrict__ out) {
    const int node = (blockIdx.x * 256 + threadIdx.x) >> 6;
    const int lane = threadIdx.x & 63;
    const int oct = lane >> 3;
    const int fl = lane & 7;
    const float ad = al_d[node];
    const int start = offsets[node];
    const int end = offsets[node + 1];

    float s = 0.f;
    float acc[8] = {};

    {
        const int idx = start + oct;
        const int src0 = csr_src[idx];
        float sc = (idx < end) ? al_s[src0] : -__builtin_inff();
        short8 v = *(const short8*)&h2[(size_t)src0 * NCLSP + fl * 8];

        for (int i = start; i < end; i += 8) {
            const int j = i + 8 + oct;
            const int nsrc = csr_src[j];
            const float nsc = (j < end) ? al_s[nsrc] : -__builtin_inff();
            const short8 nv = *(const short8*)&h2[(size_t)nsrc * NCLSP + fl * 8];
            float e_ = sc + ad;
            e_ = e_ > 0.f ? e_ : NEG_SLOPE * e_;
            const float p = __expf(e_);
            s += p;
            #pragma unroll
            for (int k = 0; k < 8; ++k)
                acc[k] = fmaf(p, bf2f((unsigned short)v[k]), acc[k]);
            sc = nsc; v = nv;
        }
    }
    s += __shfl_xor(s, 8);
    s += __shfl_xor(s, 16);
    s += __shfl_xor(s, 32);
    #pragma unroll
    for (int k = 0; k < 8; ++k) {
        acc[k] += __shfl_xor(acc[k], 8);
        acc[k] += __shfl_xor(acc[k], 16);
        acc[k] += __shfl_xor(acc[k], 32);
    }

    if (oct == 0) {
        const float inv = 1.f / (s + 1e-16f);
        float o[8];
        float mx = -1e30f;
        #pragma unroll
        for (int k = 0; k < 8; ++k) {
            const int c = fl * 8 + k;
            const float bc = (c < NCLS) ? b2[c] : 0.f;
            o[k] = acc[k] * inv + bc;
            if (c < NCLS) mx = fmaxf(mx, o[k]);
        }
        #pragma unroll
        for (int off = 1; off < 8; off <<= 1) mx = fmaxf(mx, __shfl_xor(mx, off));
        float ex = 0.f;
        #pragma unroll
        for (int k = 0; k < 8; ++k) {
            const int c = fl * 8 + k;
            if (c < NCLS) ex += __expf(o[k] - mx);
        }
        #pragma unroll
        for (int off = 1; off < 8; off <<= 1) ex += __shfl_xor(ex, off);
        const float lse = mx + logf(ex);
        if (fl < 5) {
            float4 r0, r1;
            r0.x = o[0] - lse; r0.y = o[1] - lse; r0.z = o[2] - lse; r0.w = o[3] - lse;
            r1.x = o[4] - lse; r1.y = o[5] - lse; r1.z = o[6] - lse; r1.w = o[7] - lse;
            *(float4*)&out[(size_t)node * NCLS + fl * 8] = r0;
            *(float4*)&out[(size_t)node * NCLS + fl * 8 + 4] = r1;
        }
    }
}

// ---------------- launch: 9 dispatches ---------------------------------------
extern "C" void kernel_launch(void* const* d_in, const int* in_sizes, int n_in,
                              void* d_out, int out_size, void* d_ws, size_t ws_size,
                              hipStream_t stream) {
    const float* x      = (const float*)d_in[0];
    const int*   ei     = (const int*)d_in[1];
    const float* W1     = (const float*)d_in[2];
    const float* a_src1 = (const float*)d_in[3];
    const float* a_dst1 = (const float*)d_in[4];
    const float* b1     = (const float*)d_in[5];
    const float* W2     = (const float*)d_in[6];
    const float* a_src2 = (const float*)d_in[7];
    const float* a_dst2 = (const float*)d_in[8];
    const float* b2     = (const float*)d_in[9];
    float* out = (float*)d_out;
    const int E = in_sizes[1] / 2;

    char* ws = (char*)d_ws;
    size_t off = 0;
    auto alloc = [&](size_t bytes) -> char* {
        char* p = ws + off;
        off += (bytes + 255) & ~(size_t)255;
        return p;
    };
    unsigned short* W1t   = (unsigned short*)alloc((size_t)FIN * HD * 2);
    unsigned short* W2t   = (unsigned short*)alloc((size_t)NCLSP * HD * 2);
    unsigned short* h1    = (unsigned short*)alloc((size_t)NNODES * HD * 2);
    unsigned short* h_act = (unsigned short*)alloc((size_t)NNODES * HD * 2);
    unsigned short* h2    = (unsigned short*)alloc((size_t)NNODES * NCLSP * 2);
    float* al_s1  = (float*)alloc((size_t)NNODES * HEADS * 4);
    float* al_d1  = (float*)alloc((size_t)NNODES * HEADS * 4);
    float* al_s2  = (float*)alloc((size_t)NNODES * 4);
    float* al_d2  = (float*)alloc((size_t)NNODES * 4);
    int*   deg    = (int*)alloc((size_t)NNODES * 4);   // adjacent to cursor:
    int*   cursor = (int*)alloc((size_t)NNODES * 4);   // one memset covers both
    int*   psum   = (int*)alloc((size_t)NNODES * 4);
    int*   bsum   = (int*)alloc((size_t)SBLK * 4);
    int*   offs   = (int*)alloc((size_t)(NNODES + 1) * 4);
    int*   csrsrc = (int*)alloc((size_t)E * 4 + 256);  // +64 safe pad entries

    const size_t degpad = ((size_t)NNODES * 4 + 255) & ~(size_t)255;
    hipMemsetAsync(deg, 0, degpad + (size_t)NNODES * 4, stream);

    const int eb = (E + 255) / 256;
    pre_kernel<<<eb + W1TBLK + W2TBLK, 256, 0, stream>>>(W1, W1t, W2, W2t, ei, E, eb, deg, csrsrc + E);
    scan1_kernel<<<NSCAN, SBLK, 0, stream>>>(deg, psum, bsum);
    scan23_kernel<<<NSCAN, SBLK, 0, stream>>>(deg, psum, bsum, offs);
    scatter_kernel<<<eb, 256, 0, stream>>>(ei, E, offs, cursor, csrsrc);

    gemm1_kernel<<<G1BLK, 256, 0, stream>>>(x, W1t, a_src1, a_dst1, h1, al_s1, al_d1);
    agg1_kernel<<<NNODES / 4, 256, 0, stream>>>(h1, al_s1, al_d1, offs, csrsrc, b1, h_act);
    gemm2_kernel<<<(NNODES + G2M - 1) / G2M, 256, 0, stream>>>(h_act, W2t, a_src2, a_dst2, h2, al_s2, al_d2);
    agg2_kernel<<<NNODES / 4, 256, 0, stream>>>(h2, al_s2, al_d2, offs, csrsrc, b2, out);
}

// Round 4
// 401.047 us; speedup vs baseline: 1.1368x; 1.0119x over previous
//
#include <hip/hip_runtime.h>
#include <math.h>

#define NNODES 50000
#define FIN 512
#define HID 64
#define HEADS 4
#define HD (HEADS * HID)   // 256
#define NCLS 40
#define NCLSP 64           // padded to 4x16 MFMA n-tiles; pow2 for 8-lane-per-edge agg2
#define NEG_SLOPE 0.2f
#define SBLK 256
#define NSCAN ((NNODES + SBLK - 1) / SBLK)   // 196

#define W1TBLK (FIN * HD / 256)              // 512
#define W2TBLK NCLSP                         // 64

typedef __attribute__((ext_vector_type(8))) short short8;
typedef __attribute__((ext_vector_type(4))) float f32x4;

static __device__ inline unsigned short f2bf(float f) {
    unsigned int u = __builtin_bit_cast(unsigned int, f);
    unsigned int r = (u + 0x7FFFu + ((u >> 16) & 1u)) >> 16;
    return (unsigned short)r;
}
static __device__ inline float bf2f(unsigned short b) {
    return __builtin_bit_cast(float, (unsigned int)b << 16);
}
static __device__ inline void gload_lds16(const unsigned short* g, unsigned short* l) {
    __builtin_amdgcn_global_load_lds(
        (const __attribute__((address_space(1))) unsigned int*)g,
        (__attribute__((address_space(3))) unsigned int*)l, 16, 0, 0);
}

// ---------------- preprocess: deg count + csr pad + W1t + W2t ----------------
__global__ __launch_bounds__(256) void pre_kernel(const float* __restrict__ W1,
                                                  unsigned short* __restrict__ W1t,
                                                  const float* __restrict__ W2,
                                                  unsigned short* __restrict__ W2t,
                                                  const int* __restrict__ ei, int E, int eb,
                                                  int* __restrict__ deg,
                                                  int* __restrict__ csr_pad) {
    const int b = blockIdx.x;
    const int tid = threadIdx.x;
    if (b < eb) {
        const int e = b * 256 + tid;
        if (e < E) atomicAdd(&deg[ei[E + e]], 1);
        if (b == 0 && tid < 64) csr_pad[tid] = 0;   // safe pad for clamp-free agg loops
    } else if (b < eb + W1TBLK) {
        // W1[512,256] fp32 -> W1t[256,512] bf16
        const int idx = (b - eb) * 256 + tid;
        const int k = idx >> 8;
        const int n = idx & 255;
        W1t[n * FIN + k] = f2bf(W1[idx]);
    } else {
        // W2[256,40] fp32 -> W2t[64][256] bf16, rows 40..63 zero
        const int idx = (b - eb - W1TBLK) * 256 + tid;
        const int n = idx >> 8;
        const int k = idx & 255;
        W2t[n * HD + k] = (n < NCLS) ? f2bf(W2[k * NCLS + n]) : (unsigned short)0;
    }
}

// ---------------- GEMM1: BM=64, BN=256, fused x-cast, T14 2-deep A pipeline --
// A for K-tile t is LOADED (to regs) during tile t-1's iteration and only
// ds_written (zero-wait) during tile t-1's tail -> no exposed HBM latency
// before the MFMA cluster. B via async global_load_lds DMA.
#define BM 64
#define BN 256
#define BK 32
#define G1BLK ((NNODES + BM - 1) / BM)   // 782

struct axr { float4 v0, v1; };

__global__ __launch_bounds__(256) void gemm1_kernel(const float* __restrict__ x,
                                                    const unsigned short* __restrict__ W1t,
                                                    const float* __restrict__ a_src,
                                                    const float* __restrict__ a_dst,
                                                    unsigned short* __restrict__ h1,
                                                    float* __restrict__ al_s,
                                                    float* __restrict__ al_d) {
    __shared__ unsigned short As[2][BM * BK];  // 2 x 4 KB
    __shared__ unsigned short Bs[2][BN * BK];  // 2 x 16 KB
    const int tid = threadIdx.x;
    const int wave = tid >> 6;
    const int lane = tid & 63;
    const int quad = lane >> 4;
    const int col = lane & 15;
    const int m0 = blockIdx.x * BM;
    const int srow = lane >> 2;          // 0..15 within a 16-row group
    const int skk = (lane & 3) * 8;      // 8-elem k-chunk

    const int ar = wave * 16 + srow;     // 0..63 LDS row
    const size_t agr = (size_t)min(m0 + ar, NNODES - 1) * FIN;  // clamped src row

    f32x4 acc[4][4] = {};

    auto loadA = [&](int k0) -> axr {
        axr r;
        r.v0 = *(const float4*)&x[agr + k0 + skk];
        r.v1 = *(const float4*)&x[agr + k0 + skk + 4];
        return r;
    };
    auto writeA = [&](int buf, const axr& r) {
        short8 p;
        p[0] = (short)f2bf(r.v0.x); p[1] = (short)f2bf(r.v0.y);
        p[2] = (short)f2bf(r.v0.z); p[3] = (short)f2bf(r.v0.w);
        p[4] = (short)f2bf(r.v1.x); p[5] = (short)f2bf(r.v1.y);
        p[6] = (short)f2bf(r.v1.z); p[7] = (short)f2bf(r.v1.w);
        *(short8*)&As[buf][ar * BK + skk] = p;
    };
    auto stageB = [&](int buf, int k0) {
        #pragma unroll
        for (int c = 0; c < 4; ++c) {
            const int rr = c * 64 + wave * 16 + srow;
            gload_lds16(&W1t[(size_t)rr * FIN + k0 + skk], &Bs[buf][rr * BK + skk]);
        }
    };
    auto compute = [&](int buf) {
        short8 af[4], bfv[4];
        #pragma unroll
        for (int i = 0; i < 4; ++i)
            af[i] = *(const short8*)&As[buf][(i * 16 + col) * BK + quad * 8];
        #pragma unroll
        for (int j = 0; j < 4; ++j)
            bfv[j] = *(const short8*)&Bs[buf][(wave * 64 + j * 16 + col) * BK + quad * 8];
        #pragma unroll
        for (int i = 0; i < 4; ++i)
            #pragma unroll
            for (int j = 0; j < 4; ++j)
                acc[i][j] = __builtin_amdgcn_mfma_f32_16x16x32_bf16(af[i], bfv[j], acc[i][j], 0, 0, 0);
    };

    // prologue: tile 0 into buf0; prefetch A(tile1) before the barrier that
    // drains it (so writeA in iter 1 is a zero-wait ds_write).
    axr a0 = loadA(0);
    stageB(0, 0);
    writeA(0, a0);
    axr ap = loadA(BK);
    __syncthreads();
    int cur = 0;
    for (int k0 = BK; k0 < FIN; k0 += BK) {
        stageB(cur ^ 1, k0);                       // async DMA, drains at barrier
        axr an = loadA(min(k0 + BK, FIN - BK));    // A for tile+2 (clamped dup on last)
        compute(cur);                              // MFMAs issue with no vm-wait
        writeA(cur ^ 1, ap);                       // regs drained at prior barrier
        ap = an;
        __syncthreads();
        cur ^= 1;
    }
    compute(cur);

    // epilogue: h1 write + fused per-head attention score dots (head == wave)
    float asv[4], adv[4];
    #pragma unroll
    for (int j = 0; j < 4; ++j) {
        asv[j] = a_src[wave * 64 + j * 16 + col];
        adv[j] = a_dst[wave * 64 + j * 16 + col];
    }
    #pragma unroll
    for (int i = 0; i < 4; ++i) {
        #pragma unroll
        for (int reg = 0; reg < 4; ++reg) {
            const int row = i * 16 + quad * 4 + reg;
            const int gm = m0 + row;
            float ds = 0.f, dd = 0.f;
            #pragma unroll
            for (int j = 0; j < 4; ++j) {
                const float v = acc[i][j][reg];
                ds = fmaf(v, asv[j], ds);
                dd = fmaf(v, adv[j], dd);
                if (gm < NNODES) {
                    const int gc = wave * 64 + j * 16 + col;
                    h1[(size_t)gm * HD + gc] = f2bf(v);
                }
            }
            #pragma unroll
            for (int off = 1; off < 16; off <<= 1) {
                ds += __shfl_xor(ds, off);
                dd += __shfl_xor(dd, off);
            }
            if (col == 0 && gm < NNODES) {
                al_s[gm * HEADS + wave] = ds;
                al_d[gm * HEADS + wave] = dd;
            }
        }
    }
}

// ---------------- CSR build: scans ------------------------------------------
__global__ __launch_bounds__(SBLK) void scan1_kernel(const int* __restrict__ deg,
                                                     int* __restrict__ psum,
                                                     int* __restrict__ bsum) {
    __shared__ int ws[4];
    const int t = threadIdx.x;
    const int idx = blockIdx.x * SBLK + t;
    const int lane = t & 63;
    const int w = t >> 6;
    int sv = (idx < NNODES) ? deg[idx] : 0;
    #pragma unroll
    for (int off = 1; off < 64; off <<= 1) {
        const int n = __shfl_up(sv, off);
        if (lane >= off) sv += n;
    }
    if (lane == 63) ws[w] = sv;
    __syncthreads();
    int add = 0;
    for (int i = 0; i < w; ++i) add += ws[i];
    sv += add;
    if (idx < NNODES) psum[idx] = sv;
    if (t == SBLK - 1) bsum[blockIdx.x] = sv;
}

__global__ __launch_bounds__(SBLK) void scan23_kernel(const int* __restrict__ deg,
                                                      const int* __restrict__ psum,
                                                      const int* __restrict__ bsum,
                                                      int* __restrict__ offsets) {
    __shared__ int ws[4];
    __shared__ int sc[NSCAN];
    const int t = threadIdx.x;
    const int lane = t & 63;
    const int w = t >> 6;
    int sv = (t < NSCAN) ? bsum[t] : 0;
    #pragma unroll
    for (int off = 1; off < 64; off <<= 1) {
        const int n = __shfl_up(sv, off);
        if (lane >= off) sv += n;
    }
    if (lane == 63) ws[w] = sv;
    __syncthreads();
    int add = 0;
    for (int i = 0; i < w; ++i) add += ws[i];
    sv += add;
    if (t < NSCAN) sc[t] = sv;
    __syncthreads();
    const int idx = blockIdx.x * SBLK + t;
    const int boff = (blockIdx.x > 0) ? sc[blockIdx.x - 1] : 0;
    if (idx < NNODES) offsets[idx] = psum[idx] - deg[idx] + boff;
    if (blockIdx.x == 0 && t == 0) offsets[NNODES] = sc[NSCAN - 1];
}

__global__ void scatter_kernel(const int* __restrict__ ei, int E,
                               const int* __restrict__ offsets,
                               int* __restrict__ cursor,
                               int* __restrict__ csr_src) {
    const int e = blockIdx.x * 256 + threadIdx.x;
    if (e < E) {
        const int dst = ei[E + e];
        const int src = ei[e];
        const int pos = offsets[dst] + atomicAdd(&cursor[dst], 1);
        csr_src[pos] = src;
    }
}

// ---------------- layer-1 aggregation: quarter-wave-per-edge, 4 streams ------
__global__ __launch_bounds__(256) void agg1_kernel(const unsigned short* __restrict__ h1,
                                                   const float* __restrict__ al_s,
                                                   const float* __restrict__ al_d,
                                                   const int* __restrict__ offsets,
                                                   const int* __restrict__ csr_src,
                                                   const float* __restrict__ b1,
                                                   unsigned short* __restrict__ h_act) {
    const int node = (blockIdx.x * 256 + threadIdx.x) >> 6;
    const int lane = threadIdx.x & 63;
    const int q = lane >> 4;
    const int fl = lane & 15;
    const int h = fl >> 2;
    const float ad = al_d[node * HEADS + h];
    const int start = offsets[node];
    const int end = offsets[node + 1];

    float s = 0.f;
    float acc[16] = {};

    {
        const int idx = start + q;
        const int src0 = csr_src[idx];
        float sc = (idx < end) ? al_s[src0 * HEADS + h] : -__builtin_inff();
        short8 v0 = *(const short8*)&h1[(size_t)src0 * HD + fl * 16];
        short8 v1 = *(const short8*)&h1[(size_t)src0 * HD + fl * 16 + 8];

        for (int i = start; i < end; i += 4) {
            const int j = i + 4 + q;
            const int nsrc = csr_src[j];
            const float nsc = (j < end) ? al_s[nsrc * HEADS + h] : -__builtin_inff();
            const short8 nv0 = *(const short8*)&h1[(size_t)nsrc * HD + fl * 16];
            const short8 nv1 = *(const short8*)&h1[(size_t)nsrc * HD + fl * 16 + 8];
            float e_ = sc + ad;
            e_ = e_ > 0.f ? e_ : NEG_SLOPE * e_;
            const float p = __expf(e_);
            s += p;
            #pragma unroll
            for (int k = 0; k < 8; ++k)
                acc[k] = fmaf(p, bf2f((unsigned short)v0[k]), acc[k]);
            #pragma unroll
            for (int k = 0; k < 8; ++k)
                acc[8 + k] = fmaf(p, bf2f((unsigned short)v1[k]), acc[8 + k]);
            sc = nsc; v0 = nv0; v1 = nv1;
        }
    }
    s += __shfl_xor(s, 16);
    s += __shfl_xor(s, 32);
    #pragma unroll
    for (int k = 0; k < 16; ++k) {
        acc[k] += __shfl_xor(acc[k], 16);
        acc[k] += __shfl_xor(acc[k], 32);
    }

    if (q == 0) {
        const float inv = 1.f / (s + 1e-16f);
        float bb[16];
        *(float4*)&bb[0]  = *(const float4*)&b1[fl * 16];
        *(float4*)&bb[4]  = *(const float4*)&b1[fl * 16 + 4];
        *(float4*)&bb[8]  = *(const float4*)&b1[fl * 16 + 8];
        *(float4*)&bb[12] = *(const float4*)&b1[fl * 16 + 12];
        short8 ob0, ob1;
        #pragma unroll
        for (int k = 0; k < 8; ++k) {
            const float o0 = acc[k] * inv + bb[k];
            const float o1 = acc[8 + k] * inv + bb[8 + k];
            const float e0 = o0 > 0.f ? o0 : expm1f(o0);
            const float e1 = o1 > 0.f ? o1 : expm1f(o1);
            ob0[k] = (short)f2bf(e0);
            ob1[k] = (short)f2bf(e1);
        }
        *(short8*)&h_act[(size_t)node * HD + fl * 16] = ob0;
        *(short8*)&h_act[(size_t)node * HD + fl * 16 + 8] = ob1;
    }
}

// ---------------- GEMM2 via MFMA: h2[N,64] = h_act[N,256] @ W2pad + dots -----
#define G2M 64
#define BSTRIDE 264

__global__ __launch_bounds__(256) void gemm2_kernel(const unsigned short* __restrict__ h_act,
                                                    const unsigned short* __restrict__ W2t,
                                                    const float* __restrict__ a_s2,
                                                    const float* __restrict__ a_d2,
                                                    unsigned short* __restrict__ h2,
                                                    float* __restrict__ al_s,
                                                    float* __restrict__ al_d) {
    __shared__ unsigned short Bt[NCLSP][BSTRIDE];
    const int tid = threadIdx.x;
    const int wave = tid >> 6;
    const int lane = tid & 63;
    const int quad = lane >> 4;
    const int col = lane & 15;
    const int m0 = blockIdx.x * G2M;

    #pragma unroll
    for (int it = 0; it < 8; ++it) {
        const int ch = it * 256 + tid;
        const int n = ch >> 5;
        const int c8 = (ch & 31) * 8;
        *(uint4*)&Bt[n][c8] = *(const uint4*)&W2t[(size_t)n * HD + c8];
    }

    const int rowm = m0 + wave * 16 + col;
    const int arow = min(rowm, NNODES - 1);
    short8 af[8];
    #pragma unroll
    for (int ks = 0; ks < 8; ++ks)
        af[ks] = *(const short8*)&h_act[(size_t)arow * HD + ks * 32 + quad * 8];

    __syncthreads();

    f32x4 acc[4] = {};
    #pragma unroll
    for (int j = 0; j < 4; ++j) {
        #pragma unroll
        for (int ks = 0; ks < 8; ++ks) {
            const short8 bfr = *(const short8*)&Bt[j * 16 + col][ks * 32 + quad * 8];
            acc[j] = __builtin_amdgcn_mfma_f32_16x16x32_bf16(af[ks], bfr, acc[j], 0, 0, 0);
        }
    }

    float ps[4] = {0.f, 0.f, 0.f, 0.f};
    float pd[4] = {0.f, 0.f, 0.f, 0.f};
    #pragma unroll
    for (int j = 0; j < 4; ++j) {
        const int c = j * 16 + col;
        const bool cv = c < NCLS;
        const float asc = cv ? a_s2[c] : 0.f;
        const float adc = cv ? a_d2[c] : 0.f;
        #pragma unroll
        for (int reg = 0; reg < 4; ++reg) {
            const float v = acc[j][reg];
            ps[reg] += v * asc;
            pd[reg] += v * adc;
            const int node = m0 + wave * 16 + quad * 4 + reg;
            if (node < NNODES)
                h2[(size_t)node * NCLSP + c] = f2bf(v);
        }
    }
    #pragma unroll
    for (int reg = 0; reg < 4; ++reg) {
        #pragma unroll
        for (int off = 1; off < 16; off <<= 1) {
            ps[reg] += __shfl_xor(ps[reg], off);
            pd[reg] += __shfl_xor(pd[reg], off);
        }
    }
    if (col == 0) {
        #pragma unroll
        for (int reg = 0; reg < 4; ++reg) {
            const int node = m0 + wave * 16 + quad * 4 + reg;
            if (node < NNODES) {
                al_s[node] = ps[reg];
                al_d[node] = pd[reg];
            }
        }
    }
}

// ---------------- layer-2 aggregation: octet-per-edge, 8 streams -------------
__global__ __launch_bounds__(256) void agg2_kernel(const unsigned short* __restrict__ h2,
                                                   const float* __restrict__ al_s,
                                                   const float* __restrict__ al_d,
                                                   const int* __restrict__ offsets,
                                                   const int* __restrict__ csr_src,
                                                   const float* __restrict__ b2,
                                                   float* __restrict__ out) {
    const int node = (blockIdx.x * 256 + threadIdx.x) >> 6;
    const int lane = threadIdx.x & 63;
    const int oct = lane >> 3;
    const int fl = lane & 7;
    const float ad = al_d[node];
    const int start = offsets[node];
    const int end = offsets[node + 1];

    float s = 0.f;
    float acc[8] = {};

    {
        const int idx = start + oct;
        const int src0 = csr_src[idx];
        float sc = (idx < end) ? al_s[src0] : -__builtin_inff();
        short8 v = *(const short8*)&h2[(size_t)src0 * NCLSP + fl * 8];

        for (int i = start; i < end; i += 8) {
            const int j = i + 8 + oct;
            const int nsrc = csr_src[j];
            const float nsc = (j < end) ? al_s[nsrc] : -__builtin_inff();
            const short8 nv = *(const short8*)&h2[(size_t)nsrc * NCLSP + fl * 8];
            float e_ = sc + ad;
            e_ = e_ > 0.f ? e_ : NEG_SLOPE * e_;
            const float p = __expf(e_);
            s += p;
            #pragma unroll
            for (int k = 0; k < 8; ++k)
                acc[k] = fmaf(p, bf2f((unsigned short)v[k]), acc[k]);
            sc = nsc; v = nv;
        }
    }
    s += __shfl_xor(s, 8);
    s += __shfl_xor(s, 16);
    s += __shfl_xor(s, 32);
    #pragma unroll
    for (int k = 0; k < 8; ++k) {
        acc[k] += __shfl_xor(acc[k], 8);
        acc[k] += __shfl_xor(acc[k], 16);
        acc[k] += __shfl_xor(acc[k], 32);
    }

    if (oct == 0) {
        const float inv = 1.f / (s + 1e-16f);
        float o[8];
        float mx = -1e30f;
        #pragma unroll
        for (int k = 0; k < 8; ++k) {
            const int c = fl * 8 + k;
            const float bc = (c < NCLS) ? b2[c] : 0.f;
            o[k] = acc[k] * inv + bc;
            if (c < NCLS) mx = fmaxf(mx, o[k]);
        }
        #pragma unroll
        for (int off = 1; off < 8; off <<= 1) mx = fmaxf(mx, __shfl_xor(mx, off));
        float ex = 0.f;
        #pragma unroll
        for (int k = 0; k < 8; ++k) {
            const int c = fl * 8 + k;
            if (c < NCLS) ex += __expf(o[k] - mx);
        }
        #pragma unroll
        for (int off = 1; off < 8; off <<= 1) ex += __shfl_xor(ex, off);
        const float lse = mx + logf(ex);
        if (fl < 5) {
            float4 r0, r1;
            r0.x = o[0] - lse; r0.y = o[1] - lse; r0.z = o[2] - lse; r0.w = o[3] - lse;
            r1.x = o[4] - lse; r1.y = o[5] - lse; r1.z = o[6] - lse; r1.w = o[7] - lse;
            *(float4*)&out[(size_t)node * NCLS + fl * 8] = r0;
            *(float4*)&out[(size_t)node * NCLS + fl * 8 + 4] = r1;
        }
    }
}

// ---------------- launch: 9 dispatches ---------------------------------------
extern "C" void kernel_launch(void* const* d_in, const int* in_sizes, int n_in,
                              void* d_out, int out_size, void* d_ws, size_t ws_size,
                              hipStream_t stream) {
    const float* x      = (const float*)d_in[0];
    const int*   ei     = (const int*)d_in[1];
    const float* W1     = (const float*)d_in[2];
    const float* a_src1 = (const float*)d_in[3];
    const float* a_dst1 = (const float*)d_in[4];
    const float* b1     = (const float*)d_in[5];
    const float* W2     = (const float*)d_in[6];
    const float* a_src2 = (const float*)d_in[7];
    const float* a_dst2 = (const float*)d_in[8];
    const float* b2     = (const float*)d_in[9];
    float* out = (float*)d_out;
    const int E = in_sizes[1] / 2;

    char* ws = (char*)d_ws;
    size_t off = 0;
    auto alloc = [&](size_t bytes) -> char* {
        char* p = ws + off;
        off += (bytes + 255) & ~(size_t)255;
        return p;
    };
    unsigned short* W1t   = (unsigned short*)alloc((size_t)FIN * HD * 2);
    unsigned short* W2t   = (unsigned short*)alloc((size_t)NCLSP * HD * 2);
    unsigned short* h1    = (unsigned short*)alloc((size_t)NNODES * HD * 2);
    unsigned short* h_act = (unsigned short*)alloc((size_t)NNODES * HD * 2);
    unsigned short* h2    = (unsigned short*)alloc((size_t)NNODES * NCLSP * 2);
    float* al_s1  = (float*)alloc((size_t)NNODES * HEADS * 4);
    float* al_d1  = (float*)alloc((size_t)NNODES * HEADS * 4);
    float* al_s2  = (float*)alloc((size_t)NNODES * 4);
    float* al_d2  = (float*)alloc((size_t)NNODES * 4);
    int*   deg    = (int*)alloc((size_t)NNODES * 4);   // adjacent to cursor:
    int*   cursor = (int*)alloc((size_t)NNODES * 4);   // one memset covers both
    int*   psum   = (int*)alloc((size_t)NNODES * 4);
    int*   bsum   = (int*)alloc((size_t)SBLK * 4);
    int*   offs   = (int*)alloc((size_t)(NNODES + 1) * 4);
    int*   csrsrc = (int*)alloc((size_t)E * 4 + 256);  // +64 safe pad entries

    const size_t degpad = ((size_t)NNODES * 4 + 255) & ~(size_t)255;
    hipMemsetAsync(deg, 0, degpad + (size_t)NNODES * 4, stream);

    const int eb = (E + 255) / 256;
    pre_kernel<<<eb + W1TBLK + W2TBLK, 256, 0, stream>>>(W1, W1t, W2, W2t, ei, E, eb, deg, csrsrc + E);
    scan1_kernel<<<NSCAN, SBLK, 0, stream>>>(deg, psum, bsum);
    scan23_kernel<<<NSCAN, SBLK, 0, stream>>>(deg, psum, bsum, offs);
    scatter_kernel<<<eb, 256, 0, stream>>>(ei, E, offs, cursor, csrsrc);

    gemm1_kernel<<<G1BLK, 256, 0, stream>>>(x, W1t, a_src1, a_dst1, h1, al_s1, al_d1);
    agg1_kernel<<<NNODES / 4, 256, 0, stream>>>(h1, al_s1, al_d1, offs, csrsrc, b1, h_act);
    gemm2_kernel<<<(NNODES + G2M - 1) / G2M, 256, 0, stream>>>(h_act, W2t, a_src2, a_dst2, h2, al_s2, al_d2);
    agg2_kernel<<<NNODES / 4, 256, 0, stream>>>(h2, al_s2, al_d2, offs, csrsrc, b2, out);
}